// Round 4
// baseline (283.173 us; speedup 1.0000x reference)
//
#include <hip/hip_runtime.h>
#include <hip/hip_bf16.h>

// FastBinaryLinear: y[t,o] = scale[o] * sum_i x[t,i]*sign(w[o,i])
// Pre-pass: x->bf16, w->sign(w) bf16 into d_ws. Main: 256x256 8-phase bf16
// MFMA GEMM. R4: region-split staging with minimal split vmcnt gates
// (>=5-phase lead on every gated load), bm-fastest XCD chunk decode
// (B-panel L2-resident), reads back at phase top (r2/m201 style).

typedef __bf16 bf16x8 __attribute__((ext_vector_type(8)));
typedef float f32x4 __attribute__((ext_vector_type(4)));
typedef const __attribute__((address_space(1))) void* gptr_t;
typedef __attribute__((address_space(3))) void* lptr_t;

#define LDS_BUF 65536

template<bool V> struct BoolC { static constexpr bool value = V; };

// ---- f32 -> bf16 RNE ----
__device__ __forceinline__ unsigned short f32_to_bf16_rne(float f) {
  unsigned int u = __builtin_bit_cast(unsigned int, f);
  u += 0x7fffu + ((u >> 16) & 1u);
  return (unsigned short)(u >> 16);
}

__global__ __launch_bounds__(256) void cvt_x_kernel(const float4* __restrict__ in,
                                                    ushort4* __restrict__ out, int n4) {
  int stride = gridDim.x * blockDim.x;
  for (int i = blockIdx.x * blockDim.x + threadIdx.x; i < n4; i += stride) {
    float4 f = in[i];
    ushort4 o;
    o.x = f32_to_bf16_rne(f.x);
    o.y = f32_to_bf16_rne(f.y);
    o.z = f32_to_bf16_rne(f.z);
    o.w = f32_to_bf16_rne(f.w);
    out[i] = o;
  }
}

__device__ __forceinline__ unsigned short sign_bf16(float f) {
  return f > 0.f ? (unsigned short)0x3F80u : (f < 0.f ? (unsigned short)0xBF80u : (unsigned short)0u);
}

__global__ __launch_bounds__(256) void binarize_w_kernel(const float4* __restrict__ in,
                                                         ushort4* __restrict__ out, int n4) {
  int stride = gridDim.x * blockDim.x;
  for (int i = blockIdx.x * blockDim.x + threadIdx.x; i < n4; i += stride) {
    float4 f = in[i];
    ushort4 o;
    o.x = sign_bf16(f.x);
    o.y = sign_bf16(f.y);
    o.z = sign_bf16(f.z);
    o.w = sign_bf16(f.w);
    out[i] = o;
  }
}

template<int MF0>
__device__ __forceinline__ void mfma16(f32x4 (&acc)[8][4], const bf16x8 (&a0)[2][2],
                                       const bf16x8 (&b0)[4][2]) {
#pragma unroll
  for (int j = 0; j < 2; j++)
#pragma unroll
    for (int nf = 0; nf < 4; nf++)
#pragma unroll
      for (int kk = 0; kk < 2; kk++)
        acc[MF0 + j][nf] =
            __builtin_amdgcn_mfma_f32_16x16x32_bf16(a0[j][kk], b0[nf][kk], acc[MF0 + j][nf], 0, 0, 0);
}

// ---- 256x256 8-phase GEMM: C[M][N] = A[M][K] * B[N][K]^T, per-col scale ----
__global__ __launch_bounds__(512, 2) void gemm256_kernel(
    const __hip_bfloat16* __restrict__ A,   // [M][K] bf16
    const __hip_bfloat16* __restrict__ B,   // [N][K] bf16 (+-1/0)
    const float* __restrict__ scale,        // [N]
    float* __restrict__ C,                  // [M][N] f32
    int M, int N, int K) {
  __shared__ __align__(16) char lds[131072];

  const int t = threadIdx.x;
  const int lane = t & 63;
  const int wv = t >> 6;
  const int wm = wv >> 2;   // 0..1
  const int wn = wv & 3;    // 0..3

  // T1: bijective XCD-aware swizzle; bm-FASTEST decode so each XCD chunk
  // spans few bn-panels (B-panel fits its L2).
  const int nwg = gridDim.x;
  const int bid = blockIdx.x;
  const int swz = ((nwg & 7) == 0) ? ((bid & 7) * (nwg >> 3) + (bid >> 3)) : bid;

  const int nbm = M >> 8;
  const int bm = swz % nbm;
  const int bn = swz / nbm;
  const int m0 = bm << 8, n0 = bn << 8;

  // staging: thread t's (row, col) within an 8KB issue (64 rows x 64 cols),
  // carrying the inverse granule swizzle.
  const int rlo = ((t >> 7) << 4) | ((t >> 2) & 15);
  const int gsw = (t & 3) ^ ((t >> 3) & 3);
  const int c0e = (((t >> 6) & 1) << 5) | (gsw << 3);
  const __hip_bfloat16* gA = A + (size_t)(m0 + rlo) * K + c0e;
  const __hip_bfloat16* gB = B + (size_t)(n0 + rlo) * K + c0e;
  const int stBase = wv << 10;  // wave-uniform LDS base; HW adds lane*16

  // ds_read lane bases (swizzled granule)
  const int rho = lane & 15;
  const int gpr = (lane >> 4) ^ ((lane >> 1) & 3);
  const int dsA = (wm << 14) + (rho << 6) + (gpr << 4);
  const int dsB = 32768 + ((wn >> 1) << 14) + ((wn & 1) << 13) + (rho << 6) + (gpr << 4);

#define STAGE(MAT, HALF, G64, KT, BUF)                                                   \
  __builtin_amdgcn_global_load_lds(                                                      \
      (gptr_t)(((MAT) ? gB : gA) + (size_t)((HALF)*128 + (G64)*64) * K + (size_t)(KT)*64), \
      (lptr_t)(lds + (BUF)*LDS_BUF + (MAT)*32768 + (HALF)*16384 + (G64)*8192 + stBase),  \
      16, 0, 0)

#define RD_A(MF, KK, BUF) (*(const bf16x8*)(lds + (BUF)*LDS_BUF + dsA + ((MF)*2 + (KK))*1024))
#define RD_B(NF, KK, BUF) (*(const bf16x8*)(lds + (BUF)*LDS_BUF + dsB + ((NF)*2 + (KK))*1024))
#define BAR() asm volatile("s_barrier" ::: "memory")
#define VMC(N) asm volatile("s_waitcnt vmcnt(" #N ")" ::: "memory")
#define LOAD_A_PAIR(MF, BUF)                                          \
  a0[0][0] = RD_A(MF, 0, BUF);     a0[0][1] = RD_A(MF, 1, BUF);       \
  a0[1][0] = RD_A((MF)+1, 0, BUF); a0[1][1] = RD_A((MF)+1, 1, BUF)
#define LOAD_B(BUF)                                                   \
  _Pragma("unroll")                                                   \
  for (int nf = 0; nf < 4; nf++) {                                    \
    b0[nf][0] = RD_B(nf, 0, BUF); b0[nf][1] = RD_B(nf, 1, BUF);       \
  }
#define MFMA_PH(MF0) \
  __builtin_amdgcn_s_setprio(1); mfma16<MF0>(acc, a0, b0); __builtin_amdgcn_s_setprio(0)

  f32x4 acc[8][4];
#pragma unroll
  for (int i = 0; i < 8; i++)
#pragma unroll
    for (int j = 0; j < 4; j++) acc[i][j] = (f32x4)(0.0f);

  // ---- prologue: tile 0 full (8), tile 1 B + A-hi (6). vmcnt(6) -> T0 in ----
  STAGE(0, 0, 0, 0, 0); STAGE(0, 0, 1, 0, 0); STAGE(0, 1, 0, 0, 0); STAGE(0, 1, 1, 0, 0);
  STAGE(1, 0, 0, 0, 0); STAGE(1, 0, 1, 0, 0); STAGE(1, 1, 0, 0, 0); STAGE(1, 1, 1, 0, 0);
  STAGE(1, 0, 0, 1, 1); STAGE(1, 0, 1, 1, 1); STAGE(1, 1, 0, 1, 1); STAGE(1, 1, 1, 1, 1);
  STAGE(0, 0, 1, 1, 1); STAGE(0, 1, 1, 1, 1);
  VMC(6);
  BAR();

  bf16x8 a0[2][2], b0[4][2];

  // Steady-state staging plan (FULL iter; T1=2i+1, T2=2i+2, T3=2i+3):
  //  p0: A-lo(b1,T1)   [b1 A-lo freed p7-prev]        read p6,p7; gated p5
  //  p1: B(b0,T2) x4   [b0 B freed p0]  + vmcnt(12)   gates A-lo(b0), staged p4-prev
  //  p2: A-hi(b0,T2)   [freed p1]                      read next p0,p1; gated p7
  //  p3:               vmcnt(8)                        gates B+A-hi(b1), staged p5/p6-prev
  //  p4: A-lo(b0,T2)   [freed p3]                      read next p2,p3; gated next p1
  //  p5: B(b1,T3) x4   [freed p4]  + vmcnt(12)         gates A-lo(b1), staged p0
  //  p6: A-hi(b1,T3)   [freed p5]
  //  p7:               vmcnt(8)                        gates B+A-hi(b0,T2), staged p1/p2
  auto run_iter = [&](int i, auto fullc) {
    constexpr bool FULL = decltype(fullc)::value;
    const int kt1 = 2 * i + 1, kt2 = 2 * i + 2, kt3 = 2 * i + 3;

    // ===== phase 0: tile 2i (buf0), B + mfrags 6,7 =====
    LOAD_B(0);
    LOAD_A_PAIR(6, 0);
    STAGE(0, 0, 0, kt1, 1); STAGE(0, 1, 0, kt1, 1);          // A-lo(b1,T1)
    BAR();
    MFMA_PH(6);
    BAR();

    // ===== phase 1: mfrags 4,5 =====
    LOAD_A_PAIR(4, 0);
    if constexpr (FULL) {
      STAGE(1, 0, 0, kt2, 0); STAGE(1, 0, 1, kt2, 0);        // B(b0,T2)
      STAGE(1, 1, 0, kt2, 0); STAGE(1, 1, 1, kt2, 0);
      VMC(12);                                               // gate A-lo(b0)
    } else {
      VMC(8);                                                // gate A-lo(b0)
    }
    BAR();
    MFMA_PH(4);
    BAR();

    // ===== phase 2: mfrags 2,3 =====
    LOAD_A_PAIR(2, 0);
    if constexpr (FULL) { STAGE(0, 0, 1, kt2, 0); STAGE(0, 1, 1, kt2, 0); }  // A-hi(b0,T2)
    BAR();
    MFMA_PH(2);
    BAR();

    // ===== phase 3: mfrags 0,1 =====
    LOAD_A_PAIR(0, 0);
    if constexpr (FULL) VMC(8); else VMC(2);                 // gate B+A-hi(b1)
    BAR();
    MFMA_PH(0);
    BAR();

    // ===== phase 4: tile 2i+1 (buf1), B + mfrags 6,7 =====
    LOAD_B(1);
    LOAD_A_PAIR(6, 1);
    if constexpr (FULL) { STAGE(0, 0, 0, kt2, 0); STAGE(0, 1, 0, kt2, 0); }  // A-lo(b0,T2)
    BAR();
    MFMA_PH(6);
    BAR();

    // ===== phase 5: mfrags 4,5 =====
    LOAD_A_PAIR(4, 1);
    if constexpr (FULL) {
      STAGE(1, 0, 0, kt3, 1); STAGE(1, 0, 1, kt3, 1);        // B(b1,T3)
      STAGE(1, 1, 0, kt3, 1); STAGE(1, 1, 1, kt3, 1);
      VMC(12);                                               // gate A-lo(b1)
    } else {
      VMC(0);                                                // gate A-lo(b1)
    }
    BAR();
    MFMA_PH(4);
    BAR();

    // ===== phase 6: mfrags 2,3 =====
    LOAD_A_PAIR(2, 1);
    if constexpr (FULL) { STAGE(0, 0, 1, kt3, 1); STAGE(0, 1, 1, kt3, 1); }  // A-hi(b1,T3)
    BAR();
    MFMA_PH(2);
    BAR();

    // ===== phase 7: mfrags 0,1 =====
    LOAD_A_PAIR(0, 1);
    if constexpr (FULL) VMC(8);                              // gate B+A-hi(b0,T2)
    BAR();
    MFMA_PH(0);
    BAR();
  };

  const int half_nt = K >> 7;
  for (int i = 0; i < half_nt - 1; ++i) run_iter(i, BoolC<true>{});
  run_iter(half_nt - 1, BoolC<false>{});

  // ---- epilogue: C/D layout col=lane&15, row=(lane>>4)*4+j ----
  const int cc = lane & 15;
  const int cr4 = (lane >> 4) << 2;
#pragma unroll
  for (int nf = 0; nf < 4; nf++) {
    const int col = n0 + wn * 64 + nf * 16 + cc;
    const float s = scale[col];
#pragma unroll
    for (int mf = 0; mf < 8; mf++) {
      const int row = m0 + wm * 128 + mf * 16 + cr4;
#pragma unroll
      for (int j = 0; j < 4; j++)
        C[(size_t)(row + j) * N + col] = acc[mf][nf][j] * s;
    }
  }
#undef STAGE
#undef RD_A
#undef RD_B
#undef BAR
#undef VMC
#undef LOAD_A_PAIR
#undef LOAD_B
#undef MFMA_PH
}

// ---- fallback: f32 tiled GEMM (odd shapes / tiny ws) ----
__global__ __launch_bounds__(256) void fallback_gemm_kernel(
    const float* __restrict__ x, const float* __restrict__ w,
    const float* __restrict__ scale, float* __restrict__ out,
    int M, int N, int K) {
  __shared__ float xs[16][17];
  __shared__ float ws_[16][17];
  int nb = N / 16;
  int bx = blockIdx.x % nb;
  int by = blockIdx.x / nb;
  int tx = threadIdx.x % 16;
  int ty = threadIdx.x / 16;
  float acc = 0.f;
  for (int k0 = 0; k0 < K; k0 += 16) {
    xs[ty][tx] = x[(size_t)(by * 16 + ty) * K + k0 + tx];
    float wv = w[(size_t)(bx * 16 + ty) * K + k0 + tx];
    ws_[ty][tx] = (float)((wv > 0.f) - (wv < 0.f));
    __syncthreads();
#pragma unroll
    for (int kk = 0; kk < 16; kk++) acc += xs[ty][kk] * ws_[tx][kk];
    __syncthreads();
  }
  int row = by * 16 + ty, col = bx * 16 + tx;
  out[(size_t)row * N + col] = acc * scale[col];
}

extern "C" void kernel_launch(void* const* d_in, const int* in_sizes, int n_in,
                              void* d_out, int out_size, void* d_ws, size_t ws_size,
                              hipStream_t stream) {
  const float* x = (const float*)d_in[0];
  const float* w = (const float*)d_in[1];
  const float* scale = (const float*)d_in[2];
  float* out = (float*)d_out;

  const int N = in_sizes[2];
  const int K = in_sizes[1] / N;
  const int M = in_sizes[0] / K;

  const size_t xb_bytes = (size_t)M * K * 2;
  const size_t wb_bytes = (size_t)N * K * 2;
  const bool shapes_ok = (M % 256 == 0) && (N % 256 == 0) && (K % 128 == 0);

  if (shapes_ok && ws_size >= xb_bytes + wb_bytes) {
    __hip_bfloat16* xb = (__hip_bfloat16*)d_ws;
    __hip_bfloat16* wb = (__hip_bfloat16*)((char*)d_ws + xb_bytes);

    cvt_x_kernel<<<2048, 256, 0, stream>>>((const float4*)x, (ushort4*)xb, M * (K / 4));
    binarize_w_kernel<<<2048, 256, 0, stream>>>((const float4*)w, (ushort4*)wb, N * (K / 4));

    int grid = (M / 256) * (N / 256);
    gemm256_kernel<<<grid, 512, 0, stream>>>(xb, wb, scale, out, M, N, K);
  } else {
    int grid = (M / 16) * (N / 16);
    fallback_gemm_kernel<<<grid, 256, 0, stream>>>(x, w, scale, out, M, N, K);
  }
}

// Round 5
// 189.832 us; speedup vs baseline: 1.4917x; 1.4917x over previous
//
#include <hip/hip_runtime.h>
#include <hip/hip_bf16.h>

// FastBinaryLinear: y[t,o] = scale[o] * sum_i x[t,i]*sign(w[o,i])
// R5: i8 path. x quantized per-row to i8 (alpha_t = rowmax/127), w -> sign
// as i8 {-1,0,1}; i32-exact MFMA accumulate via mfma_i32_16x16x64_i8.
// GEMM is the r2 8-phase 256x256 schedule, byte-identical LDS layout
// (K-tile = 128 bytes/row), epilogue scales by alpha[row]*scale[col].

typedef int i32x4 __attribute__((ext_vector_type(4)));
typedef const __attribute__((address_space(1))) void* gptr_t;
typedef __attribute__((address_space(3))) void* lptr_t;

#define LDS_BUF 65536

template<bool V> struct BoolC { static constexpr bool value = V; };

// ---- per-row quantize x: alpha = max|x|/127, q = rint(x/alpha) ----
__global__ __launch_bounds__(256) void quant_x_kernel(const float4* __restrict__ x,
                                                      unsigned* __restrict__ xq,
                                                      float* __restrict__ alpha, int K) {
  const int row = blockIdx.x;
  const int t = threadIdx.x;
  const int n4 = K >> 2;
  const float4* xr = x + (size_t)row * n4;
  unsigned* qr = xq + (size_t)row * n4;

  float m = 0.f;
  for (int i = t; i < n4; i += 256) {
    float4 v = xr[i];
    m = fmaxf(m, fmaxf(fmaxf(fabsf(v.x), fabsf(v.y)), fmaxf(fabsf(v.z), fabsf(v.w))));
  }
  for (int o = 32; o > 0; o >>= 1) m = fmaxf(m, __shfl_xor(m, o));
  __shared__ float wm[4];
  if ((t & 63) == 0) wm[t >> 6] = m;
  __syncthreads();
  m = fmaxf(fmaxf(wm[0], wm[1]), fmaxf(wm[2], wm[3]));

  const float inv = m > 0.f ? 127.f / m : 0.f;
  if (t == 0) alpha[row] = m > 0.f ? m / 127.f : 0.f;

  for (int i = t; i < n4; i += 256) {
    float4 v = xr[i];  // L1-resident re-read (row = 16KB)
    int q0 = (int)rintf(v.x * inv), q1 = (int)rintf(v.y * inv);
    int q2 = (int)rintf(v.z * inv), q3 = (int)rintf(v.w * inv);
    qr[i] = (unsigned)(q0 & 255) | ((unsigned)(q1 & 255) << 8) |
            ((unsigned)(q2 & 255) << 16) | ((unsigned)(q3 & 255) << 24);
  }
}

// ---- w -> sign(w) as i8 {-1,0,+1} ----
__global__ __launch_bounds__(256) void binarize_w_i8(const float4* __restrict__ in,
                                                     unsigned* __restrict__ out, int n4) {
  int stride = gridDim.x * blockDim.x;
  for (int i = blockIdx.x * blockDim.x + threadIdx.x; i < n4; i += stride) {
    float4 f = in[i];
    int s0 = (f.x > 0.f) - (f.x < 0.f);
    int s1 = (f.y > 0.f) - (f.y < 0.f);
    int s2 = (f.z > 0.f) - (f.z < 0.f);
    int s3 = (f.w > 0.f) - (f.w < 0.f);
    out[i] = (unsigned)(s0 & 255) | ((unsigned)(s1 & 255) << 8) |
             ((unsigned)(s2 & 255) << 16) | ((unsigned)(s3 & 255) << 24);
  }
}

template<int MF0>
__device__ __forceinline__ void mfma16(i32x4 (&acc)[8][4], const i32x4 (&a0)[2][2],
                                       const i32x4 (&b0)[4][2]) {
#pragma unroll
  for (int j = 0; j < 2; j++)
#pragma unroll
    for (int nf = 0; nf < 4; nf++)
#pragma unroll
      for (int kk = 0; kk < 2; kk++)
        acc[MF0 + j][nf] =
            __builtin_amdgcn_mfma_i32_16x16x64_i8(a0[j][kk], b0[nf][kk], acc[MF0 + j][nf], 0, 0, 0);
}

// ---- 256x256 8-phase i8 GEMM: C = A[M][K]i8 * B[N][K]^T i8, i32 exact ----
// LDS byte-geometry identical to the verified bf16 r2 kernel: half-tile =
// 128 rows x 128 B; subtile 16r x 64B; granule XOR swizzle key=(row>>1)&3.
__global__ __launch_bounds__(512, 2) void gemm256_i8_kernel(
    const signed char* __restrict__ A,   // [M][K] i8 (quantized x)
    const signed char* __restrict__ B,   // [N][K] i8 (sign w)
    const float* __restrict__ scale,     // [N]
    const float* __restrict__ alpha,     // [M]
    float* __restrict__ C,               // [M][N] f32
    int M, int N, int K) {
  __shared__ __align__(16) char lds[131072];

  const int t = threadIdx.x;
  const int lane = t & 63;
  const int wv = t >> 6;
  const int wm = wv >> 2;   // 0..1
  const int wn = wv & 3;    // 0..3

  const int nbn = N >> 8;
  const int bn = blockIdx.x % nbn;
  const int bm = blockIdx.x / nbn;
  const int m0 = bm << 8, n0 = bn << 8;

  // staging coords: 8KB issue = 64 rows x 128 bytes; inverse granule swizzle
  const int rlo = ((t >> 7) << 4) | ((t >> 2) & 15);
  const int gsw = (t & 3) ^ ((t >> 3) & 3);
  const int c0b = (((t >> 6) & 1) << 6) | (gsw << 4);   // byte col
  const signed char* gA = A + (size_t)(m0 + rlo) * K + c0b;
  const signed char* gB = B + (size_t)(n0 + rlo) * K + c0b;
  const int stBase = wv << 10;  // wave-uniform LDS base; HW adds lane*16

  // ds_read lane bases (swizzled granule), all in bytes
  const int rho = lane & 15;
  const int gpr = (lane >> 4) ^ ((lane >> 1) & 3);
  const int dsA = (wm << 14) + (rho << 6) + (gpr << 4);
  const int dsB = 32768 + ((wn >> 1) << 14) + ((wn & 1) << 13) + (rho << 6) + (gpr << 4);

#define STAGE(MAT, HALF, G64, KT, BUF)                                                    \
  __builtin_amdgcn_global_load_lds(                                                       \
      (gptr_t)(((MAT) ? gB : gA) + (size_t)((HALF)*128 + (G64)*64) * K + (size_t)(KT)*128), \
      (lptr_t)(lds + (BUF)*LDS_BUF + (MAT)*32768 + (HALF)*16384 + (G64)*8192 + stBase),   \
      16, 0, 0)

#define RD_A(MF, KK, BUF) (*(const i32x4*)(lds + (BUF)*LDS_BUF + dsA + ((MF)*2 + (KK))*1024))
#define RD_B(NF, KK, BUF) (*(const i32x4*)(lds + (BUF)*LDS_BUF + dsB + ((NF)*2 + (KK))*1024))
#define BAR() asm volatile("s_barrier" ::: "memory")
#define LOAD_A_PAIR(MF, BUF)                                          \
  a0[0][0] = RD_A(MF, 0, BUF);     a0[0][1] = RD_A(MF, 1, BUF);       \
  a0[1][0] = RD_A((MF)+1, 0, BUF); a0[1][1] = RD_A((MF)+1, 1, BUF)
#define LOAD_B(BUF)                                                   \
  _Pragma("unroll")                                                   \
  for (int nf = 0; nf < 4; nf++) {                                    \
    b0[nf][0] = RD_B(nf, 0, BUF); b0[nf][1] = RD_B(nf, 1, BUF);       \
  }

  i32x4 acc[8][4];
#pragma unroll
  for (int i = 0; i < 8; i++)
#pragma unroll
    for (int j = 0; j < 4; j++) acc[i][j] = (i32x4)(0);

  // ---- prologue: tile 0 fully (8 loads), tile 1 B + A-hi (6 loads) ----
  STAGE(0, 0, 0, 0, 0); STAGE(0, 0, 1, 0, 0); STAGE(0, 1, 0, 0, 0); STAGE(0, 1, 1, 0, 0);
  STAGE(1, 0, 0, 0, 0); STAGE(1, 0, 1, 0, 0); STAGE(1, 1, 0, 0, 0); STAGE(1, 1, 1, 0, 0);
  STAGE(1, 0, 0, 1, 1); STAGE(1, 0, 1, 1, 1); STAGE(1, 1, 0, 1, 1); STAGE(1, 1, 1, 1, 1);
  STAGE(0, 0, 1, 1, 1); STAGE(0, 1, 1, 1, 1);
  asm volatile("s_waitcnt vmcnt(6)" ::: "memory");
  BAR();

  i32x4 a0[2][2], b0[4][2];

  auto run_iter = [&](int i, auto fullc) {
    constexpr bool FULL = decltype(fullc)::value;
    const int kt1 = 2 * i + 1, kt2 = 2 * i + 2, kt3 = 2 * i + 3;

    // ===== phase 0: tile 2i (buf0), B + mfrags 6,7 =====
    LOAD_B(0);
    LOAD_A_PAIR(6, 0);
    STAGE(0, 0, 0, kt1, 1); STAGE(0, 1, 0, kt1, 1);          // A-lo(b1, T1)
    BAR();
    __builtin_amdgcn_s_setprio(1); mfma16<6>(acc, a0, b0); __builtin_amdgcn_s_setprio(0);
    BAR();

    // ===== phase 1: mfrags 4,5 =====
    LOAD_A_PAIR(4, 0);
    if constexpr (FULL) { STAGE(1, 0, 0, kt2, 0); STAGE(1, 0, 1, kt2, 0); }  // B-lo(b0,T2)
    BAR();
    __builtin_amdgcn_s_setprio(1); mfma16<4>(acc, a0, b0); __builtin_amdgcn_s_setprio(0);
    BAR();

    // ===== phase 2: mfrags 2,3 =====
    LOAD_A_PAIR(2, 0);
    if constexpr (FULL) { STAGE(1, 1, 0, kt2, 0); STAGE(1, 1, 1, kt2, 0); }  // B-hi(b0,T2)
    BAR();
    __builtin_amdgcn_s_setprio(1); mfma16<2>(acc, a0, b0); __builtin_amdgcn_s_setprio(0);
    BAR();

    // ===== phase 3: mfrags 0,1; vmcnt gate -> buf1 resident =====
    LOAD_A_PAIR(0, 0);
    if constexpr (FULL) { STAGE(0, 0, 1, kt2, 0); STAGE(0, 1, 1, kt2, 0); }  // A-hi(b0,T2)
    BAR();
    __builtin_amdgcn_s_setprio(1); mfma16<0>(acc, a0, b0); __builtin_amdgcn_s_setprio(0);
    if constexpr (FULL) asm volatile("s_waitcnt vmcnt(6)" ::: "memory");
    else                asm volatile("s_waitcnt vmcnt(0)" ::: "memory");
    BAR();

    // ===== phase 4: tile 2i+1 (buf1), B + mfrags 6,7 =====
    LOAD_B(1);
    LOAD_A_PAIR(6, 1);
    if constexpr (FULL) { STAGE(0, 0, 0, kt2, 0); STAGE(0, 1, 0, kt2, 0); }  // A-lo(b0,T2)
    BAR();
    __builtin_amdgcn_s_setprio(1); mfma16<6>(acc, a0, b0); __builtin_amdgcn_s_setprio(0);
    BAR();

    // ===== phase 5: mfrags 4,5 =====
    LOAD_A_PAIR(4, 1);
    if constexpr (FULL) { STAGE(1, 0, 0, kt3, 1); STAGE(1, 0, 1, kt3, 1); }  // B-lo(b1,T3)
    BAR();
    __builtin_amdgcn_s_setprio(1); mfma16<4>(acc, a0, b0); __builtin_amdgcn_s_setprio(0);
    BAR();

    // ===== phase 6: mfrags 2,3 =====
    LOAD_A_PAIR(2, 1);
    if constexpr (FULL) { STAGE(1, 1, 0, kt3, 1); STAGE(1, 1, 1, kt3, 1); }  // B-hi(b1,T3)
    BAR();
    __builtin_amdgcn_s_setprio(1); mfma16<2>(acc, a0, b0); __builtin_amdgcn_s_setprio(0);
    BAR();

    // ===== phase 7: mfrags 0,1; vmcnt gate -> next buf0 resident =====
    LOAD_A_PAIR(0, 1);
    if constexpr (FULL) { STAGE(0, 0, 1, kt3, 1); STAGE(0, 1, 1, kt3, 1); }  // A-hi(b1,T3)
    BAR();
    __builtin_amdgcn_s_setprio(1); mfma16<0>(acc, a0, b0); __builtin_amdgcn_s_setprio(0);
    if constexpr (FULL) asm volatile("s_waitcnt vmcnt(6)" ::: "memory");
    else                asm volatile("s_waitcnt vmcnt(0)" ::: "memory");
    BAR();
  };

  const int half_nt = K >> 8;   // 256 i8 elems per iter (2 tiles x 128)
  for (int i = 0; i < half_nt - 1; ++i) run_iter(i, BoolC<true>{});
  run_iter(half_nt - 1, BoolC<false>{});

  // ---- epilogue: C/D col=lane&15, row=(lane>>4)*4+j; y = acc*alpha*scale ----
  const int cc = lane & 15;
  const int cr4 = (lane >> 4) << 2;
#pragma unroll
  for (int nf = 0; nf < 4; nf++) {
    const int col = n0 + wn * 64 + nf * 16 + cc;
    const float s = scale[col];
#pragma unroll
    for (int mf = 0; mf < 8; mf++) {
      const int row = m0 + wm * 128 + mf * 16 + cr4;
#pragma unroll
      for (int j = 0; j < 4; j++)
        C[(size_t)(row + j) * N + col] = (float)acc[mf][nf][j] * (s * alpha[row + j]);
    }
  }
#undef STAGE
#undef RD_A
#undef RD_B
#undef BAR
#undef LOAD_A_PAIR
#undef LOAD_B
}

// ---- fallback: f32 tiled GEMM (odd shapes / tiny ws) ----
__global__ __launch_bounds__(256) void fallback_gemm_kernel(
    const float* __restrict__ x, const float* __restrict__ w,
    const float* __restrict__ scale, float* __restrict__ out,
    int M, int N, int K) {
  __shared__ float xs[16][17];
  __shared__ float ws_[16][17];
  int nb = N / 16;
  int bx = blockIdx.x % nb;
  int by = blockIdx.x / nb;
  int tx = threadIdx.x % 16;
  int ty = threadIdx.x / 16;
  float acc = 0.f;
  for (int k0 = 0; k0 < K; k0 += 16) {
    xs[ty][tx] = x[(size_t)(by * 16 + ty) * K + k0 + tx];
    float wv = w[(size_t)(bx * 16 + ty) * K + k0 + tx];
    ws_[ty][tx] = (float)((wv > 0.f) - (wv < 0.f));
    __syncthreads();
#pragma unroll
    for (int kk = 0; kk < 16; kk++) acc += xs[ty][kk] * ws_[tx][kk];
    __syncthreads();
  }
  int row = by * 16 + ty, col = bx * 16 + tx;
  out[(size_t)row * N + col] = acc * scale[col];
}

extern "C" void kernel_launch(void* const* d_in, const int* in_sizes, int n_in,
                              void* d_out, int out_size, void* d_ws, size_t ws_size,
                              hipStream_t stream) {
  const float* x = (const float*)d_in[0];
  const float* w = (const float*)d_in[1];
  const float* scale = (const float*)d_in[2];
  float* out = (float*)d_out;

  const int N = in_sizes[2];
  const int K = in_sizes[1] / N;
  const int M = in_sizes[0] / K;

  const size_t xq_bytes = (size_t)M * K;
  const size_t wq_bytes = (size_t)N * K;
  const size_t al_bytes = (size_t)M * 4;
  const bool shapes_ok = (M % 256 == 0) && (N % 256 == 0) && (K % 1024 == 0);

  if (shapes_ok && ws_size >= xq_bytes + wq_bytes + al_bytes) {
    signed char* xq = (signed char*)d_ws;
    signed char* wq = (signed char*)((char*)d_ws + xq_bytes);
    float* alpha = (float*)((char*)d_ws + xq_bytes + wq_bytes);

    quant_x_kernel<<<M, 256, 0, stream>>>((const float4*)x, (unsigned*)xq, alpha, K);
    binarize_w_i8<<<2048, 256, 0, stream>>>((const float4*)w, (unsigned*)wq, N * (K / 4));

    int grid = (M / 256) * (N / 256);
    gemm256_i8_kernel<<<grid, 512, 0, stream>>>(xq, wq, scale, alpha, out, M, N, K);
  } else {
    int grid = (M / 16) * (N / 16);
    fallback_gemm_kernel<<<grid, 256, 0, stream>>>(x, w, scale, out, M, N, K);
  }
}

// Round 6
// 186.917 us; speedup vs baseline: 1.5150x; 1.0156x over previous
//
#include <hip/hip_runtime.h>
#include <hip/hip_bf16.h>

// FastBinaryLinear: y[t,o] = scale[o] * sum_i x[t,i]*sign(w[o,i])
// R6: i8 path, 4-phase schedule (32 MFMA/phase) to halve per-phase barrier
// overhead; fused pre-pass (row-quant x + sign(w)) in one launch.
// LDS byte geometry identical to verified r5 kernel.

typedef int i32x4 __attribute__((ext_vector_type(4)));
typedef const __attribute__((address_space(1))) void* gptr_t;
typedef __attribute__((address_space(3))) void* lptr_t;

#define LDS_BUF 65536

template<bool V> struct BoolC { static constexpr bool value = V; };

// ---- fused pre-pass: blocks [0,M) quantize x rows; [M, M+N) sign w rows ----
__global__ __launch_bounds__(256) void prep_kernel(
    const float4* __restrict__ x, const float4* __restrict__ w,
    unsigned* __restrict__ xq, unsigned* __restrict__ wq,
    float* __restrict__ alpha, int M, int N, int K) {
  const int bid = blockIdx.x;
  const int t = threadIdx.x;
  const int n4 = K >> 2;

  if (bid < M) {
    const int row = bid;
    const float4* xr = x + (size_t)row * n4;
    unsigned* qr = xq + (size_t)row * n4;

    float m = 0.f;
    for (int i = t; i < n4; i += 256) {
      float4 v = xr[i];
      m = fmaxf(m, fmaxf(fmaxf(fabsf(v.x), fabsf(v.y)), fmaxf(fabsf(v.z), fabsf(v.w))));
    }
    for (int o = 32; o > 0; o >>= 1) m = fmaxf(m, __shfl_xor(m, o));
    __shared__ float wm[4];
    if ((t & 63) == 0) wm[t >> 6] = m;
    __syncthreads();
    m = fmaxf(fmaxf(wm[0], wm[1]), fmaxf(wm[2], wm[3]));

    const float inv = m > 0.f ? 127.f / m : 0.f;
    if (t == 0) alpha[row] = m > 0.f ? m / 127.f : 0.f;

    for (int i = t; i < n4; i += 256) {
      float4 v = xr[i];  // L1-resident re-read (row = 16KB)
      int q0 = (int)rintf(v.x * inv), q1 = (int)rintf(v.y * inv);
      int q2 = (int)rintf(v.z * inv), q3 = (int)rintf(v.w * inv);
      qr[i] = (unsigned)(q0 & 255) | ((unsigned)(q1 & 255) << 8) |
              ((unsigned)(q2 & 255) << 16) | ((unsigned)(q3 & 255) << 24);
    }
  } else {
    const int row = bid - M;
    const float4* wr = w + (size_t)row * n4;
    unsigned* qr = wq + (size_t)row * n4;
    for (int i = t; i < n4; i += 256) {
      float4 f = wr[i];
      int s0 = (f.x > 0.f) - (f.x < 0.f);
      int s1 = (f.y > 0.f) - (f.y < 0.f);
      int s2 = (f.z > 0.f) - (f.z < 0.f);
      int s3 = (f.w > 0.f) - (f.w < 0.f);
      qr[i] = (unsigned)(s0 & 255) | ((unsigned)(s1 & 255) << 8) |
              ((unsigned)(s2 & 255) << 16) | ((unsigned)(s3 & 255) << 24);
    }
  }
}

// 32 MFMA cluster: mf-quad MF0..MF0+3 x 4 nf x 2 kk, kk outermost so the
// dependent pair on each acc[j][nf] is 16 instructions apart.
template<int MF0>
__device__ __forceinline__ void mfma32(i32x4 (&acc)[8][4], const i32x4 (&a0)[4][2],
                                       const i32x4 (&b0)[4][2]) {
#pragma unroll
  for (int kk = 0; kk < 2; kk++)
#pragma unroll
    for (int j = 0; j < 4; j++)
#pragma unroll
      for (int nf = 0; nf < 4; nf++)
        acc[MF0 + j][nf] =
            __builtin_amdgcn_mfma_i32_16x16x64_i8(a0[j][kk], b0[nf][kk], acc[MF0 + j][nf], 0, 0, 0);
}

// ---- 256x256 4-phase i8 GEMM: C = A[M][K]i8 * B[N][K]^T i8, i32 exact ----
__global__ __launch_bounds__(512, 2) void gemm256_i8_kernel(
    const signed char* __restrict__ A,   // [M][K] i8 (quantized x)
    const signed char* __restrict__ B,   // [N][K] i8 (sign w)
    const float* __restrict__ scale,     // [N]
    const float* __restrict__ alpha,     // [M]
    float* __restrict__ C,               // [M][N] f32
    int M, int N, int K) {
  __shared__ __align__(16) char lds[131072];

  const int t = threadIdx.x;
  const int lane = t & 63;
  const int wv = t >> 6;
  const int wm = wv >> 2;   // 0..1
  const int wn = wv & 3;    // 0..3

  const int nbn = N >> 8;
  const int bn = blockIdx.x % nbn;
  const int bm = blockIdx.x / nbn;
  const int m0 = bm << 8, n0 = bn << 8;

  // staging coords: 8KB issue = 64 rows x 128 bytes; inverse granule swizzle
  const int rlo = ((t >> 7) << 4) | ((t >> 2) & 15);
  const int gsw = (t & 3) ^ ((t >> 3) & 3);
  const int c0b = (((t >> 6) & 1) << 6) | (gsw << 4);   // byte col
  const signed char* gA = A + (size_t)(m0 + rlo) * K + c0b;
  const signed char* gB = B + (size_t)(n0 + rlo) * K + c0b;
  const int stBase = wv << 10;  // wave-uniform LDS base; HW adds lane*16

  // ds_read lane bases (swizzled granule), all in bytes
  const int rho = lane & 15;
  const int gpr = (lane >> 4) ^ ((lane >> 1) & 3);
  const int dsA = (wm << 14) + (rho << 6) + (gpr << 4);
  const int dsB = 32768 + ((wn >> 1) << 14) + ((wn & 1) << 13) + (rho << 6) + (gpr << 4);

#define STAGE(MAT, HALF, G64, KT, BUF)                                                    \
  __builtin_amdgcn_global_load_lds(                                                       \
      (gptr_t)(((MAT) ? gB : gA) + (size_t)((HALF)*128 + (G64)*64) * K + (size_t)(KT)*128), \
      (lptr_t)(lds + (BUF)*LDS_BUF + (MAT)*32768 + (HALF)*16384 + (G64)*8192 + stBase),   \
      16, 0, 0)
#define STAGE_FULL(MAT, KT, BUF)                                      \
  STAGE(MAT, 0, 0, KT, BUF); STAGE(MAT, 0, 1, KT, BUF);               \
  STAGE(MAT, 1, 0, KT, BUF); STAGE(MAT, 1, 1, KT, BUF)

#define RD_A(MF, KK, BUF) (*(const i32x4*)(lds + (BUF)*LDS_BUF + dsA + ((MF)*2 + (KK))*1024))
#define RD_B(NF, KK, BUF) (*(const i32x4*)(lds + (BUF)*LDS_BUF + dsB + ((NF)*2 + (KK))*1024))
#define BAR() asm volatile("s_barrier" ::: "memory")
#define VMC(N) asm volatile("s_waitcnt vmcnt(" #N ")" ::: "memory")
#define LOAD_A_QUAD(MF0, BUF)                                         \
  _Pragma("unroll")                                                   \
  for (int j = 0; j < 4; j++) {                                       \
    a0[j][0] = RD_A((MF0) + j, 0, BUF);                               \
    a0[j][1] = RD_A((MF0) + j, 1, BUF);                               \
  }
#define LOAD_B(BUF)                                                   \
  _Pragma("unroll")                                                   \
  for (int nf = 0; nf < 4; nf++) {                                    \
    b0[nf][0] = RD_B(nf, 0, BUF); b0[nf][1] = RD_B(nf, 1, BUF);       \
  }
#define MFMA_PH(MF0) \
  __builtin_amdgcn_s_setprio(1); mfma32<MF0>(acc, a0, b0); __builtin_amdgcn_s_setprio(0)

  i32x4 acc[8][4];
#pragma unroll
  for (int i = 0; i < 8; i++)
#pragma unroll
    for (int j = 0; j < 4; j++) acc[i][j] = (i32x4)(0);

  // ---- prologue: b0 <- T0 full (A+B), b1 <- B(T1). vmcnt(4) -> T0 in ----
  STAGE_FULL(0, 0, 0);
  STAGE_FULL(1, 0, 0);
  STAGE_FULL(1, 1, 1);
  VMC(4);
  BAR();

  i32x4 a0[4][2], b0[4][2];

  // Steady state (T0=2i->b0, T1=2i+1->b1, T2=2i+2->b0, T3=2i+3->b1):
  //  P0: compute b0 mf4-7;  STAGE A(b1,T1)           [A(b1) freed prev P3]
  //  P1: compute b0 mf0-3;  STAGE B(b0,T2); VMC(4)   [B(b0) freed P0; gate->b1 ready]
  //  P2: compute b1 mf4-7;  STAGE A(b0,T2)           [A(b0) freed P1]
  //  P3: compute b1 mf0-3;  STAGE B(b1,T3); VMC(4)   [B(b1) freed P2; gate->b0 ready]
  auto run_iter = [&](int i, auto fullc) {
    constexpr bool FULL = decltype(fullc)::value;
    const int kt1 = 2 * i + 1, kt2 = 2 * i + 2, kt3 = 2 * i + 3;

    // ===== P0: tile 2i (b0), mf 4..7 =====
    LOAD_B(0);
    LOAD_A_QUAD(4, 0);
    STAGE_FULL(0, kt1, 1);                       // A(b1,T1)
    BAR();
    MFMA_PH(4);
    BAR();

    // ===== P1: mf 0..3; gate for b1 =====
    LOAD_A_QUAD(0, 0);
    if constexpr (FULL) { STAGE_FULL(1, kt2, 0); VMC(4); }  // B(b0,T2)
    else                { VMC(0); }
    BAR();
    MFMA_PH(0);
    BAR();

    // ===== P2: tile 2i+1 (b1), mf 4..7 =====
    LOAD_B(1);
    LOAD_A_QUAD(4, 1);
    if constexpr (FULL) { STAGE_FULL(0, kt2, 0); }          // A(b0,T2)
    BAR();
    MFMA_PH(4);
    BAR();

    // ===== P3: mf 0..3; gate for b0 =====
    LOAD_A_QUAD(0, 1);
    if constexpr (FULL) { STAGE_FULL(1, kt3, 1); VMC(4); }  // B(b1,T3)
    BAR();
    MFMA_PH(0);
    BAR();
  };

  const int half_nt = K >> 8;   // 256 i8 elems per iter (2 tiles x 128B)
  for (int i = 0; i < half_nt - 1; ++i) run_iter(i, BoolC<true>{});
  run_iter(half_nt - 1, BoolC<false>{});

  // ---- epilogue: C/D col=lane&15, row=(lane>>4)*4+j; y = acc*alpha*scale ----
  const int cc = lane & 15;
  const int cr4 = (lane >> 4) << 2;
#pragma unroll
  for (int nf = 0; nf < 4; nf++) {
    const int col = n0 + wn * 64 + nf * 16 + cc;
    const float s = scale[col];
#pragma unroll
    for (int mf = 0; mf < 8; mf++) {
      const int row = m0 + wm * 128 + mf * 16 + cr4;
#pragma unroll
      for (int j = 0; j < 4; j++)
        C[(size_t)(row + j) * N + col] = (float)acc[mf][nf][j] * (s * alpha[row + j]);
    }
  }
#undef STAGE
#undef STAGE_FULL
#undef RD_A
#undef RD_B
#undef BAR
#undef VMC
#undef LOAD_A_QUAD
#undef LOAD_B
#undef MFMA_PH
}

// ---- fallback: f32 tiled GEMM (odd shapes / tiny ws) ----
__global__ __launch_bounds__(256) void fallback_gemm_kernel(
    const float* __restrict__ x, const float* __restrict__ w,
    const float* __restrict__ scale, float* __restrict__ out,
    int M, int N, int K) {
  __shared__ float xs[16][17];
  __shared__ float ws_[16][17];
  int nb = N / 16;
  int bx = blockIdx.x % nb;
  int by = blockIdx.x / nb;
  int tx = threadIdx.x % 16;
  int ty = threadIdx.x / 16;
  float acc = 0.f;
  for (int k0 = 0; k0 < K; k0 += 16) {
    xs[ty][tx] = x[(size_t)(by * 16 + ty) * K + k0 + tx];
    float wv = w[(size_t)(bx * 16 + ty) * K + k0 + tx];
    ws_[ty][tx] = (float)((wv > 0.f) - (wv < 0.f));
    __syncthreads();
#pragma unroll
    for (int kk = 0; kk < 16; kk++) acc += xs[ty][kk] * ws_[tx][kk];
    __syncthreads();
  }
  int row = by * 16 + ty, col = bx * 16 + tx;
  out[(size_t)row * N + col] = acc * scale[col];
}

extern "C" void kernel_launch(void* const* d_in, const int* in_sizes, int n_in,
                              void* d_out, int out_size, void* d_ws, size_t ws_size,
                              hipStream_t stream) {
  const float* x = (const float*)d_in[0];
  const float* w = (const float*)d_in[1];
  const float* scale = (const float*)d_in[2];
  float* out = (float*)d_out;

  const int N = in_sizes[2];
  const int K = in_sizes[1] / N;
  const int M = in_sizes[0] / K;

  const size_t xq_bytes = (size_t)M * K;
  const size_t wq_bytes = (size_t)N * K;
  const size_t al_bytes = (size_t)M * 4;
  const bool shapes_ok = (M % 256 == 0) && (N % 256 == 0) && (K % 1024 == 0);

  if (shapes_ok && ws_size >= xq_bytes + wq_bytes + al_bytes) {
    signed char* xq = (signed char*)d_ws;
    signed char* wq = (signed char*)((char*)d_ws + xq_bytes);
    float* alpha = (float*)((char*)d_ws + xq_bytes + wq_bytes);

    prep_kernel<<<M + N, 256, 0, stream>>>((const float4*)x, (const float4*)w,
                                           (unsigned*)xq, (unsigned*)wq, alpha, M, N, K);

    int grid = (M / 256) * (N / 256);
    gemm256_i8_kernel<<<grid, 512, 0, stream>>>(xq, wq, scale, alpha, out, M, N, K);
  } else {
    int grid = (M / 16) * (N / 16);
    fallback_gemm_kernel<<<grid, 256, 0, stream>>>(x, w, scale, out, M, N, K);
  }
}